// Round 3
// baseline (223.092 us; speedup 1.0000x reference)
//
#include <hip/hip_runtime.h>
#include <hip/hip_cooperative_groups.h>
#include <math.h>

namespace cg = cooperative_groups;

// Problem constants (from setup_inputs)
#define D 1024
#define M 8192
#define N 16384
#define EPS 1e-8

#define IN_BLOCKS 512               // input sign-count blocks, 32 rows each
#define EM_BLOCKS 256               // embed sum/sumsq blocks, 32 rows each
#define GRID_BLOCKS (IN_BLOCKS + EM_BLOCKS)
#define ROWS 32
#define RED_BLOCKS 64               // phase-2: 16 columns per block

// ws layout:
//   pSign [IN_BLOCKS][D] f32   (2 MB)
//   pS    [EM_BLOCKS][D] f32   (1 MB)
//   pQ    [EM_BLOCKS][D] f32   (1 MB)
//   blockRes [RED_BLOCKS] f64

__global__ __launch_bounds__(256) void fused_kernel(const float* __restrict__ input,
                                                    const float* __restrict__ embed,
                                                    float* __restrict__ pSign,
                                                    float* __restrict__ pS,
                                                    float* __restrict__ pQ,
                                                    double* __restrict__ blockRes,
                                                    float* __restrict__ out) {
    cg::grid_group grid = cg::this_grid();

    __shared__ double ls[3][4][16];
    __shared__ double contrib[16];

    const int b = blockIdx.x;
    const int t = threadIdx.x;
    const int col = t * 4;

    // ---------------- phase 1: stream both tensors ----------------
    if (b < IN_BLOCKS) {
        const size_t r0 = (size_t)b * ROWS;
        float4 s = make_float4(0.f, 0.f, 0.f, 0.f);
#pragma unroll 4
        for (int r = 0; r < ROWS; ++r) {
            float4 v = *reinterpret_cast<const float4*>(input + (r0 + r) * D + col);
            s.x += (v.x > 0.f ? 1.f : 0.f) - (v.x < 0.f ? 1.f : 0.f);
            s.y += (v.y > 0.f ? 1.f : 0.f) - (v.y < 0.f ? 1.f : 0.f);
            s.z += (v.z > 0.f ? 1.f : 0.f) - (v.z < 0.f ? 1.f : 0.f);
            s.w += (v.w > 0.f ? 1.f : 0.f) - (v.w < 0.f ? 1.f : 0.f);
        }
        *reinterpret_cast<float4*>(pSign + (size_t)b * D + col) = s;
    } else {
        const int e = b - IN_BLOCKS;
        const size_t r0 = (size_t)e * ROWS;
        float4 s = make_float4(0.f, 0.f, 0.f, 0.f);
        float4 q = make_float4(0.f, 0.f, 0.f, 0.f);
#pragma unroll 4
        for (int r = 0; r < ROWS; ++r) {
            float4 v = *reinterpret_cast<const float4*>(embed + (r0 + r) * D + col);
            s.x += v.x; s.y += v.y; s.z += v.z; s.w += v.w;
            q.x += v.x * v.x; q.y += v.y * v.y; q.z += v.z * v.z; q.w += v.w * v.w;
        }
        *reinterpret_cast<float4*>(pS + (size_t)e * D + col) = s;
        *reinterpret_cast<float4*>(pQ + (size_t)e * D + col) = q;
    }

    grid.sync();

    // ---------------- phase 2: 64 blocks reduce 16 columns each ----------------
    if (b < RED_BLOCKS) {
        const int g = t >> 4;        // 0..15 stripe over source blocks
        const int c = t & 15;        // 0..15 column within this block's slice
        const int d = b * 16 + c;

        double sgn = 0.0, se = 0.0, qq = 0.0;
        for (int bb = g; bb < IN_BLOCKS; bb += 16)
            sgn += (double)pSign[(size_t)bb * D + d];
        for (int bb = g; bb < EM_BLOCKS; bb += 16) {
            se += (double)pS[(size_t)bb * D + d];
            qq += (double)pQ[(size_t)bb * D + d];
        }

        // fold the 4 stripes-per-wave (lanes differing by 16, 32)
        sgn += __shfl_xor(sgn, 16); sgn += __shfl_xor(sgn, 32);
        se  += __shfl_xor(se, 16);  se  += __shfl_xor(se, 32);
        qq  += __shfl_xor(qq, 16);  qq  += __shfl_xor(qq, 32);

        const int wid = t >> 6;
        const int lane = t & 63;
        if (lane < 16) { ls[0][wid][lane] = sgn; ls[1][wid][lane] = se; ls[2][wid][lane] = qq; }
        __syncthreads();

        if (t < 16) {
            double S = ls[0][0][t] + ls[0][1][t] + ls[0][2][t] + ls[0][3][t];
            double E = ls[1][0][t] + ls[1][1][t] + ls[1][2][t] + ls[1][3][t];
            double Q = ls[2][0][t] + ls[2][1][t] + ls[2][2][t] + ls[2][3][t];
            double n2 = sqrt(Q);
            // term sum for column d: (s_e / (sqrt(M)*max(n2,eps))) * signcount
            contrib[t] = (E / (90.50966799187809 * fmax(n2, EPS))) * S;
        }
        __syncthreads();
        if (t == 0) {
            double acc = 0.0;
            for (int i = 0; i < 16; ++i) acc += contrib[i];   // fixed order
            blockRes[b] = acc;
        }
    }

    grid.sync();

    // ---------------- phase 3: block 0 folds 64 doubles ----------------
    if (b == 0 && t < 64) {
        double a = blockRes[t];
        for (int off = 32; off > 0; off >>= 1) a += __shfl_down(a, off);
        if (t == 0) out[0] = (float)a;
    }
}

extern "C" void kernel_launch(void* const* d_in, const int* in_sizes, int n_in,
                              void* d_out, int out_size, void* d_ws, size_t ws_size,
                              hipStream_t stream) {
    const float* input = (const float*)d_in[0];   // [N, D]
    const float* embed = (const float*)d_in[1];   // [M, D]
    float* out = (float*)d_out;

    char* ws = (char*)d_ws;
    float* pSign = (float*)ws;                                        // 512*1024 f32
    float* pS = pSign + (size_t)IN_BLOCKS * D;                        // 256*1024 f32
    float* pQ = pS + (size_t)EM_BLOCKS * D;                           // 256*1024 f32
    double* blockRes = (double*)(pQ + (size_t)EM_BLOCKS * D);         // 64 f64

    void* args[] = {(void*)&input, (void*)&embed, (void*)&pSign, (void*)&pS,
                    (void*)&pQ, (void*)&blockRes, (void*)&out};
    hipLaunchCooperativeKernel((const void*)fused_kernel, dim3(GRID_BLOCKS), dim3(256),
                               args, 0, stream);
}

// Round 4
// 113.240 us; speedup vs baseline: 1.9701x; 1.9701x over previous
//
#include <hip/hip_runtime.h>
#include <math.h>

// Problem constants (from setup_inputs)
#define D 1024
#define M 8192
#define N 16384

#define IN_BLOCKS 512               // input sign-count blocks, 32 rows each
#define EM_BLOCKS 256               // embed sum/sumsq blocks, 32 rows each
#define GRID_BLOCKS (IN_BLOCKS + EM_BLOCKS)
#define ROWS 32
#define SIGN_SH 8                   // shadow copies for sign accumulator (int)
#define EM_SH 4                     // shadow copies for sum / sumsq (double)

// ws layout (zeroed by hipMemsetAsync each call):
//   sgnAcc [SIGN_SH][D] int     32 KB
//   sAcc   [EM_SH][D]  double   32 KB
//   qAcc   [EM_SH][D]  double   32 KB
//   counter              int     4 B
#define WS_ZERO_BYTES (SIGN_SH * D * 4 + EM_SH * D * 8 * 2 + 4)

__global__ __launch_bounds__(256) void fused_kernel(const float* __restrict__ input,
                                                    const float* __restrict__ embed,
                                                    int* __restrict__ sgnAcc,
                                                    double* __restrict__ sAcc,
                                                    double* __restrict__ qAcc,
                                                    int* __restrict__ counter,
                                                    float* __restrict__ out) {
    const int b = blockIdx.x;
    const int t = threadIdx.x;
    const int col = t * 4;

    // ---------------- phase 1: stream + atomic accumulate ----------------
    if (b < IN_BLOCKS) {
        const size_t r0 = (size_t)b * ROWS;
        int s0 = 0, s1 = 0, s2 = 0, s3 = 0;
#pragma unroll 8
        for (int r = 0; r < ROWS; ++r) {
            float4 v = *reinterpret_cast<const float4*>(input + (r0 + r) * D + col);
            s0 += (v.x > 0.f) - (v.x < 0.f);
            s1 += (v.y > 0.f) - (v.y < 0.f);
            s2 += (v.z > 0.f) - (v.z < 0.f);
            s3 += (v.w > 0.f) - (v.w < 0.f);
        }
        int* a = sgnAcc + (size_t)(b & (SIGN_SH - 1)) * D + col;
        atomicAdd(a + 0, s0);
        atomicAdd(a + 1, s1);
        atomicAdd(a + 2, s2);
        atomicAdd(a + 3, s3);
    } else {
        const int e = b - IN_BLOCKS;
        const size_t r0 = (size_t)e * ROWS;
        float4 s = make_float4(0.f, 0.f, 0.f, 0.f);
        float4 q = make_float4(0.f, 0.f, 0.f, 0.f);
#pragma unroll 8
        for (int r = 0; r < ROWS; ++r) {
            float4 v = *reinterpret_cast<const float4*>(embed + (r0 + r) * D + col);
            s.x += v.x; s.y += v.y; s.z += v.z; s.w += v.w;
            q.x += v.x * v.x; q.y += v.y * v.y; q.z += v.z * v.z; q.w += v.w * v.w;
        }
        double* sa = sAcc + (size_t)(e & (EM_SH - 1)) * D + col;
        double* qa = qAcc + (size_t)(e & (EM_SH - 1)) * D + col;
        unsafeAtomicAdd(sa + 0, (double)s.x);
        unsafeAtomicAdd(sa + 1, (double)s.y);
        unsafeAtomicAdd(sa + 2, (double)s.z);
        unsafeAtomicAdd(sa + 3, (double)s.w);
        unsafeAtomicAdd(qa + 0, (double)q.x);
        unsafeAtomicAdd(qa + 1, (double)q.y);
        unsafeAtomicAdd(qa + 2, (double)q.z);
        unsafeAtomicAdd(qa + 3, (double)q.w);
    }

    // ---------------- ticket: last block finishes ----------------
    __threadfence();          // make this thread's atomics device-visible
    __syncthreads();          // all threads in block done + fenced
    __shared__ int isLast;
    if (t == 0) {
        int old = atomicAdd(counter, 1);
        isLast = (old == GRID_BLOCKS - 1);
    }
    __syncthreads();
    if (!isLast) return;
    __threadfence();          // invalidate L1 so we see everyone's atomics

    // ---------------- phase 2: last block computes the scalar ----------------
    // thread t handles columns col..col+3
    double acc = 0.0;
#pragma unroll
    for (int j = 0; j < 4; ++j) {
        const int d = col + j;
        int S = 0;
#pragma unroll
        for (int k = 0; k < SIGN_SH; ++k) S += sgnAcc[(size_t)k * D + d];
        double E = 0.0, Q = 0.0;
#pragma unroll
        for (int k = 0; k < EM_SH; ++k) {
            E += sAcc[(size_t)k * D + d];
            Q += qAcc[(size_t)k * D + d];
        }
        double n2 = sqrt(Q);
        // per-column term sum: (s_e / (sqrt(M) * max(n2, eps))) * signcount
        acc += (E / (90.50966799187809 * fmax(n2, 1e-8))) * (double)S;
    }

    // block reduce 256 doubles -> scalar (fixed order across waves)
    for (int off = 32; off > 0; off >>= 1) acc += __shfl_down(acc, off);
    __shared__ double wsum[4];
    const int lane = t & 63;
    const int wid = t >> 6;
    if (lane == 0) wsum[wid] = acc;
    __syncthreads();
    if (t == 0) out[0] = (float)(wsum[0] + wsum[1] + wsum[2] + wsum[3]);
}

extern "C" void kernel_launch(void* const* d_in, const int* in_sizes, int n_in,
                              void* d_out, int out_size, void* d_ws, size_t ws_size,
                              hipStream_t stream) {
    const float* input = (const float*)d_in[0];   // [N, D]
    const float* embed = (const float*)d_in[1];   // [M, D]
    float* out = (float*)d_out;

    char* ws = (char*)d_ws;
    int* sgnAcc = (int*)ws;                                   // SIGN_SH * D ints
    double* sAcc = (double*)(ws + SIGN_SH * D * 4);           // EM_SH * D doubles
    double* qAcc = sAcc + (size_t)EM_SH * D;                  // EM_SH * D doubles
    int* counter = (int*)(ws + SIGN_SH * D * 4 + EM_SH * D * 8 * 2);

    hipMemsetAsync(ws, 0, WS_ZERO_BYTES, stream);
    fused_kernel<<<GRID_BLOCKS, 256, 0, stream>>>(input, embed, sgnAcc, sAcc, qAcc,
                                                  counter, out);
}

// Round 5
// 48.155 us; speedup vs baseline: 4.6328x; 2.3516x over previous
//
#include <hip/hip_runtime.h>
#include <math.h>

// Problem constants (from setup_inputs)
#define D 1024
#define M 8192
#define N 16384
#define EPS 1e-8

#define ROWS 16                      // rows per streaming block
#define IN_BLOCKS (N / ROWS)         // 1024
#define EM_BLOCKS (M / ROWS)         // 512
#define GRID1 (IN_BLOCKS + EM_BLOCKS)
#define RED_BLOCKS 64                // reduce kernel: 16 columns per block

// ws layout:
//   pSign [IN_BLOCKS][D] signed char  (1 MB)
//   pS    [EM_BLOCKS][D] f32          (2 MB)
//   pQ    [EM_BLOCKS][D] f32          (2 MB)
//   blockRes [RED_BLOCKS] f64
//   counter  int  (zeroed each call)

__global__ __launch_bounds__(256) void stream_kernel(const float* __restrict__ input,
                                                     const float* __restrict__ embed,
                                                     signed char* __restrict__ pSign,
                                                     float* __restrict__ pS,
                                                     float* __restrict__ pQ) {
    const int b = blockIdx.x;
    const int t = threadIdx.x;
    const int col = t * 4;

    if (b < IN_BLOCKS) {
        const float4* src = reinterpret_cast<const float4*>(input + (size_t)b * ROWS * D + col);
        int s0 = 0, s1 = 0, s2 = 0, s3 = 0;
#pragma unroll
        for (int r = 0; r < ROWS; ++r) {
            float4 v = src[(size_t)r * (D / 4)];
            s0 += (v.x > 0.f) - (v.x < 0.f);
            s1 += (v.y > 0.f) - (v.y < 0.f);
            s2 += (v.z > 0.f) - (v.z < 0.f);
            s3 += (v.w > 0.f) - (v.w < 0.f);
        }
        char4 packed;
        packed.x = (signed char)s0; packed.y = (signed char)s1;
        packed.z = (signed char)s2; packed.w = (signed char)s3;
        *reinterpret_cast<char4*>(pSign + (size_t)b * D + col) = packed;
    } else {
        const int e = b - IN_BLOCKS;
        const float4* src = reinterpret_cast<const float4*>(embed + (size_t)e * ROWS * D + col);
        float4 s = make_float4(0.f, 0.f, 0.f, 0.f);
        float4 q = make_float4(0.f, 0.f, 0.f, 0.f);
#pragma unroll
        for (int r = 0; r < ROWS; ++r) {
            float4 v = src[(size_t)r * (D / 4)];
            s.x += v.x; s.y += v.y; s.z += v.z; s.w += v.w;
            q.x += v.x * v.x; q.y += v.y * v.y; q.z += v.z * v.z; q.w += v.w * v.w;
        }
        *reinterpret_cast<float4*>(pS + (size_t)e * D + col) = s;
        *reinterpret_cast<float4*>(pQ + (size_t)e * D + col) = q;
    }
}

// K2: 64 blocks, 16 columns each; last block (ticket) folds the 64 partials.
__global__ __launch_bounds__(256) void reduce_kernel(const signed char* __restrict__ pSign,
                                                     const float* __restrict__ pS,
                                                     const float* __restrict__ pQ,
                                                     double* __restrict__ blockRes,
                                                     int* __restrict__ counter,
                                                     float* __restrict__ out) {
    const int t = threadIdx.x;
    const int g = t >> 4;        // 0..15 stripe over source rows
    const int c = t & 15;        // 0..15 column within slice
    const int d = blockIdx.x * 16 + c;

    int sgn = 0;
    for (int bb = g; bb < IN_BLOCKS; bb += 16)
        sgn += (int)pSign[(size_t)bb * D + d];
    double se = 0.0, qq = 0.0;
    for (int bb = g; bb < EM_BLOCKS; bb += 16) {
        se += (double)pS[(size_t)bb * D + d];
        qq += (double)pQ[(size_t)bb * D + d];
    }

    // fold the 4 stripes per wave (lanes differing by 16, 32)
    sgn += __shfl_xor(sgn, 16); sgn += __shfl_xor(sgn, 32);
    se  += __shfl_xor(se, 16);  se  += __shfl_xor(se, 32);
    qq  += __shfl_xor(qq, 16);  qq  += __shfl_xor(qq, 32);

    __shared__ double ls[3][4][16];
    __shared__ double contrib[16];
    const int wid = t >> 6;
    const int lane = t & 63;
    if (lane < 16) { ls[0][wid][lane] = (double)sgn; ls[1][wid][lane] = se; ls[2][wid][lane] = qq; }
    __syncthreads();

    if (t < 16) {
        double S = ls[0][0][t] + ls[0][1][t] + ls[0][2][t] + ls[0][3][t];
        double E = ls[1][0][t] + ls[1][1][t] + ls[1][2][t] + ls[1][3][t];
        double Q = ls[2][0][t] + ls[2][1][t] + ls[2][2][t] + ls[2][3][t];
        double n2 = sqrt(Q);
        // per-column term sum: (s_e / (sqrt(M)*max(n2,eps))) * signcount
        contrib[t] = (E / (90.50966799187809 * fmax(n2, EPS))) * S;
    }
    __syncthreads();
    if (t == 0) {
        double acc = 0.0;
        for (int i = 0; i < 16; ++i) acc += contrib[i];   // fixed order
        __hip_atomic_store(&blockRes[blockIdx.x], acc, __ATOMIC_RELEASE,
                           __HIP_MEMORY_SCOPE_AGENT);
    }

    // ---- ticket: last finishing block folds the 64 results ----
    __shared__ int isLast;
    if (t == 0) {
        int old = __hip_atomic_fetch_add(counter, 1, __ATOMIC_ACQ_REL,
                                         __HIP_MEMORY_SCOPE_AGENT);
        isLast = (old == RED_BLOCKS - 1);
    }
    __syncthreads();
    if (isLast && t < 64) {
        double a = __hip_atomic_load(&blockRes[t], __ATOMIC_ACQUIRE,
                                     __HIP_MEMORY_SCOPE_AGENT);
        for (int off = 32; off > 0; off >>= 1) a += __shfl_down(a, off);
        if (t == 0) out[0] = (float)a;
    }
}

extern "C" void kernel_launch(void* const* d_in, const int* in_sizes, int n_in,
                              void* d_out, int out_size, void* d_ws, size_t ws_size,
                              hipStream_t stream) {
    const float* input = (const float*)d_in[0];   // [N, D]
    const float* embed = (const float*)d_in[1];   // [M, D]
    float* out = (float*)d_out;

    char* ws = (char*)d_ws;
    signed char* pSign = (signed char*)ws;                              // 1 MB
    float* pS = (float*)(ws + (size_t)IN_BLOCKS * D);                   // 2 MB
    float* pQ = pS + (size_t)EM_BLOCKS * D;                             // 2 MB
    double* blockRes = (double*)(pQ + (size_t)EM_BLOCKS * D);           // 64 f64
    int* counter = (int*)(blockRes + RED_BLOCKS);

    hipMemsetAsync(counter, 0, sizeof(int), stream);
    stream_kernel<<<GRID1, 256, 0, stream>>>(input, embed, pSign, pS, pQ);
    reduce_kernel<<<RED_BLOCKS, 256, 0, stream>>>(pSign, pS, pQ, blockRes, counter, out);
}

// Round 6
// 38.614 us; speedup vs baseline: 5.7775x; 1.2471x over previous
//
#include <hip/hip_runtime.h>
#include <math.h>

// Problem constants (from setup_inputs)
#define D 1024
#define M 8192
#define N 16384
#define EPS 1e-8

#define ROWS 32                      // rows per streaming block
#define IN_BLOCKS (N / ROWS)         // 512
#define EM_BLOCKS (M / ROWS)         // 256
#define GRID1 (IN_BLOCKS + EM_BLOCKS) // 768
#define RED_BLOCKS 64                // reduce kernel: 16 columns per block

// ws layout:
//   pSign [IN_BLOCKS][D] f32   (2 MB)
//   pS    [EM_BLOCKS][D] f32   (1 MB)
//   pQ    [EM_BLOCKS][D] f32   (1 MB)
//   blockRes [RED_BLOCKS] f64
//   counter  int   (zeroed by K1 each call — no memset node)

// K1: proven R2 streaming kernel + counter reset.
__global__ __launch_bounds__(256) void stream_kernel(const float* __restrict__ input,
                                                     const float* __restrict__ embed,
                                                     float* __restrict__ pSign,
                                                     float* __restrict__ pS,
                                                     float* __restrict__ pQ,
                                                     int* __restrict__ counter) {
    const int b = blockIdx.x;
    const int t = threadIdx.x;
    const int col = t * 4;

    if (b == 0 && t == 0) *counter = 0;  // visible to K2 via kernel-boundary release

    if (b < IN_BLOCKS) {
        const size_t r0 = (size_t)b * ROWS;
        float4 s = make_float4(0.f, 0.f, 0.f, 0.f);
#pragma unroll 4
        for (int r = 0; r < ROWS; ++r) {
            float4 v = *reinterpret_cast<const float4*>(input + (r0 + r) * D + col);
            s.x += (v.x > 0.f ? 1.f : 0.f) - (v.x < 0.f ? 1.f : 0.f);
            s.y += (v.y > 0.f ? 1.f : 0.f) - (v.y < 0.f ? 1.f : 0.f);
            s.z += (v.z > 0.f ? 1.f : 0.f) - (v.z < 0.f ? 1.f : 0.f);
            s.w += (v.w > 0.f ? 1.f : 0.f) - (v.w < 0.f ? 1.f : 0.f);
        }
        *reinterpret_cast<float4*>(pSign + (size_t)b * D + col) = s;
    } else {
        const int e = b - IN_BLOCKS;
        const size_t r0 = (size_t)e * ROWS;
        float4 s = make_float4(0.f, 0.f, 0.f, 0.f);
        float4 q = make_float4(0.f, 0.f, 0.f, 0.f);
#pragma unroll 4
        for (int r = 0; r < ROWS; ++r) {
            float4 v = *reinterpret_cast<const float4*>(embed + (r0 + r) * D + col);
            s.x += v.x; s.y += v.y; s.z += v.z; s.w += v.w;
            q.x += v.x * v.x; q.y += v.y * v.y; q.z += v.z * v.z; q.w += v.w * v.w;
        }
        *reinterpret_cast<float4*>(pS + (size_t)e * D + col) = s;
        *reinterpret_cast<float4*>(pQ + (size_t)e * D + col) = q;
    }
}

// K2: 64 blocks, 16 columns each; last block (ticket) folds the 64 partials.
__global__ __launch_bounds__(256) void reduce_kernel(const float* __restrict__ pSign,
                                                     const float* __restrict__ pS,
                                                     const float* __restrict__ pQ,
                                                     double* __restrict__ blockRes,
                                                     int* __restrict__ counter,
                                                     float* __restrict__ out) {
    const int t = threadIdx.x;
    const int g = t >> 4;        // 0..15 stripe over source blocks
    const int c = t & 15;        // 0..15 column within this block's slice
    const int d = blockIdx.x * 16 + c;

    double sgn = 0.0, se = 0.0, qq = 0.0;
    for (int bb = g; bb < IN_BLOCKS; bb += 16)
        sgn += (double)pSign[(size_t)bb * D + d];
    for (int bb = g; bb < EM_BLOCKS; bb += 16) {
        se += (double)pS[(size_t)bb * D + d];
        qq += (double)pQ[(size_t)bb * D + d];
    }

    // fold the 4 stripes per wave (lanes differing by 16, 32)
    sgn += __shfl_xor(sgn, 16); sgn += __shfl_xor(sgn, 32);
    se  += __shfl_xor(se, 16);  se  += __shfl_xor(se, 32);
    qq  += __shfl_xor(qq, 16);  qq  += __shfl_xor(qq, 32);

    __shared__ double ls[3][4][16];
    __shared__ double contrib[16];
    const int wid = t >> 6;
    const int lane = t & 63;
    if (lane < 16) { ls[0][wid][lane] = sgn; ls[1][wid][lane] = se; ls[2][wid][lane] = qq; }
    __syncthreads();

    if (t < 16) {
        double S = ls[0][0][t] + ls[0][1][t] + ls[0][2][t] + ls[0][3][t];
        double E = ls[1][0][t] + ls[1][1][t] + ls[1][2][t] + ls[1][3][t];
        double Q = ls[2][0][t] + ls[2][1][t] + ls[2][2][t] + ls[2][3][t];
        double n2 = sqrt(Q);
        // per-column term sum: (s_e / (sqrt(M)*max(n2,eps))) * signcount
        contrib[t] = (E / (90.50966799187809 * fmax(n2, EPS))) * S;
    }
    __syncthreads();
    if (t == 0) {
        double acc = 0.0;
        for (int i = 0; i < 16; ++i) acc += contrib[i];   // fixed order
        __hip_atomic_store(&blockRes[blockIdx.x], acc, __ATOMIC_RELEASE,
                           __HIP_MEMORY_SCOPE_AGENT);
    }

    // ---- ticket: last finishing block folds the 64 results ----
    __shared__ int isLast;
    if (t == 0) {
        int old = __hip_atomic_fetch_add(counter, 1, __ATOMIC_ACQ_REL,
                                         __HIP_MEMORY_SCOPE_AGENT);
        isLast = (old == RED_BLOCKS - 1);
    }
    __syncthreads();
    if (isLast && t < 64) {
        double a = __hip_atomic_load(&blockRes[t], __ATOMIC_ACQUIRE,
                                     __HIP_MEMORY_SCOPE_AGENT);
        for (int off = 32; off > 0; off >>= 1) a += __shfl_down(a, off);
        if (t == 0) out[0] = (float)a;
    }
}

extern "C" void kernel_launch(void* const* d_in, const int* in_sizes, int n_in,
                              void* d_out, int out_size, void* d_ws, size_t ws_size,
                              hipStream_t stream) {
    const float* input = (const float*)d_in[0];   // [N, D]
    const float* embed = (const float*)d_in[1];   // [M, D]
    float* out = (float*)d_out;

    char* ws = (char*)d_ws;
    float* pSign = (float*)ws;                                        // 512*1024 f32
    float* pS = pSign + (size_t)IN_BLOCKS * D;                        // 256*1024 f32
    float* pQ = pS + (size_t)EM_BLOCKS * D;                           // 256*1024 f32
    double* blockRes = (double*)(pQ + (size_t)EM_BLOCKS * D);         // 64 f64
    int* counter = (int*)(blockRes + RED_BLOCKS);

    stream_kernel<<<GRID1, 256, 0, stream>>>(input, embed, pSign, pS, pQ, counter);
    reduce_kernel<<<RED_BLOCKS, 256, 0, stream>>>(pSign, pS, pQ, blockRes, counter, out);
}